// Round 19
// baseline (13156.526 us; speedup 1.0000x reference)
//
#include <hip/hip_runtime.h>
#include <hip/hip_fp16.h>
#include <math.h>

#define B 64
#define T_READ 128
#define L_WRITE 32
#define TT 160
#define D 256
#define R 1024
#define N 512
#define M 128
#define HD 524
#define K5K 1152
#define EPS 1e-8f
#define BNM ((size_t)B*N*M)

__device__ __forceinline__ float sigmoidf(float x){ return 1.0f/(1.0f+expf(-x)); }
__device__ __forceinline__ float softplusf(float x){ return (x > 20.f) ? x : log1pf(expf(x)); }

// ---------- one-time: transpose x -> xT[t][k][b] ----------
__global__ __launch_bounds__(256) void kx_transpose(const float* __restrict__ x, float* __restrict__ xT){
    __shared__ float tile[64][65];
    const int t = blockIdx.x >> 2, k0 = (blockIdx.x & 3)*64;
    #pragma unroll
    for (int rep = 0; rep < 16; ++rep){
        int idx = rep*256 + threadIdx.x;
        int bl = idx >> 6, kl = idx & 63;
        tile[bl][kl] = x[((size_t)bl*T_READ + t)*D + k0 + kl];
    }
    __syncthreads();
    #pragma unroll
    for (int rep = 0; rep < 16; ++rep){
        int idx = rep*256 + threadIdx.x;
        int kl = idx >> 6, bl = idx & 63;
        xT[((size_t)t*D + k0 + kl)*64 + bl] = tile[bl][kl];
    }
}

// ---------- one-time: pack Wl/Ul into fp16 Wreh[bk2][k][8]; block bk2 owns cols {q*1024+bk2*2+i} ----------
__global__ __launch_bounds__(256) void kpack_w(const float* __restrict__ Wl, const float* __restrict__ Ul,
                                               __half* __restrict__ Wreh){
    const int k = blockIdx.x;                 // 0..1407
    const float* src = (k < 384) ? (Wl + (size_t)k*4096) : (Ul + (size_t)(k-384)*4096);
    #pragma unroll
    for (int it = 0; it < 16; ++it){
        int j = it*256 + threadIdx.x;         // 0..4095
        int bk2 = j >> 3, r = j & 7, q = r >> 1, i = r & 1;
        Wreh[((size_t)bk2*1408 + k)*8 + r] = __float2half_rn(src[q*1024 + bk2*2 + i]);
    }
}

// ---------- one-time: Wh -> fp16 copy ----------
__global__ __launch_bounds__(256) void kpack_wh(const float* __restrict__ Wh, __half* __restrict__ Whh){
    const int k = blockIdx.x;                 // 0..1023
    for (int j = threadIdx.x; j < HD; j += 256)
        Whh[(size_t)k*HD + j] = __float2half_rn(Wh[(size_t)k*HD + j]);
}

// ---------- one-time: init state ----------
__global__ void k_init(float* ht, float* c_t, float* rp, float* wst, __half* Mem){
    size_t idx = (size_t)blockIdx.x*blockDim.x + threadIdx.x;
    size_t stride = (size_t)gridDim.x*blockDim.x;
    const __half mi = __float2half(1e-6f);
    for (size_t i = idx; i < BNM; i += stride) Mem[i] = mi;
    for (size_t i = idx; i < R*64; i += stride){ ht[i]=0.f; c_t[i]=0.f; }
    for (size_t i = idx; i < 8*128*64; i += stride) rp[i] = 0.f;
    for (size_t i = idx; i < 4*B*N; i += stride) wst[i] = 1.f/512.f;
}

// ---------- K1: combine 8 rp partials; z-GEMM; LSTM gates. grid 512 x 1024 (8 cols/block) ----------
__global__ __launch_bounds__(1024) void k1_z(
    const float* __restrict__ xT, const __half* __restrict__ Wreh, const float* __restrict__ bl,
    float* __restrict__ ht, float* __restrict__ c_t, const float* __restrict__ rp,
    float* __restrict__ hist, int t)
{
    __shared__ float smem[8192 + 8192];   // [0,8192) reads staging, comb 16x8x64
    const int bk = blockIdx.x;            // 0..511
    const int tid = threadIdx.x, lane = tid & 63, w = tid >> 6;   // w: 0..15

    for (int e = tid; e < 8192; e += 1024){
        float s = 0.f;
        #pragma unroll
        for (int p = 0; p < 8; ++p) s += rp[p*8192 + e];
        smem[e] = s;
        if (t > T_READ && (e >> 10) == bk)
            hist[((size_t)(t-1-T_READ)*K5K + 1024 + (e>>6))*64 + (e&63)] = s;
    }
    __syncthreads();

    const int rd = (t < T_READ);
    const int kn = rd ? 88 : 72;
    const int k0 = rd ? w*88 : 256 + w*72;
    const __half* wbase = Wreh + ((size_t)bk*1408 + k0)*8;
    float acc[8];
    #pragma unroll
    for (int i = 0; i < 8; ++i) acc[i] = 0.f;
    #pragma unroll 4
    for (int kk = 0; kk < kn; ++kk){
        int k = k0 + kk;
        float a;
        if (k < 256)      a = xT[((size_t)t*256 + k)*64 + lane];
        else if (k < 384) a = smem[(k-256)*64 + lane];
        else              a = ht[(size_t)(k-384)*64 + lane];
        float4 raw = *reinterpret_cast<const float4*>(wbase + (size_t)kk*8);
        const __half2* h0 = reinterpret_cast<const __half2*>(&raw);
        float2 f;
        f = __half22float2(h0[0]); acc[0] += a*f.x; acc[1] += a*f.y;
        f = __half22float2(h0[1]); acc[2] += a*f.x; acc[3] += a*f.y;
        f = __half22float2(h0[2]); acc[4] += a*f.x; acc[5] += a*f.y;
        f = __half22float2(h0[3]); acc[6] += a*f.x; acc[7] += a*f.y;
    }
    float* comb = smem + 8192;
    #pragma unroll
    for (int j = 0; j < 8; ++j) comb[(w*8 + j)*64 + lane] = acc[j];
    __syncthreads();
    if (tid < 128){
        int i = tid >> 6, b2 = tid & 63;      // i: 0..1 local col
        float g4[4];
        #pragma unroll
        for (int q = 0; q < 4; ++q){
            float s = bl[q*1024 + bk*2 + i];
            #pragma unroll
            for (int ks = 0; ks < 16; ++ks) s += comb[(ks*8 + q*2 + i)*64 + b2];
            g4[q] = s;
        }
        int ri = (bk*2 + i)*64 + b2;
        float cn = sigmoidf(g4[1])*c_t[ri] + sigmoidf(g4[0])*tanhf(g4[2]);
        float hn = sigmoidf(g4[3])*tanhf(cn);
        c_t[ri] = cn;
        ht[ri] = hn;
        if (t >= T_READ) hist[((size_t)(t-T_READ)*K5K + bk*2 + i)*64 + b2] = hn;
    }
}

// ---------- K2f: head GEMM + finalize, fused. grid 262 x 512 ----------
__global__ __launch_bounds__(512) void k2f(
    const float* __restrict__ ht, const __half* __restrict__ Whh, const float* __restrict__ bh,
    float* __restrict__ khat, float* __restrict__ scal, float* __restrict__ eal)
{
    __shared__ float part[8][2][64];
    const int tid = threadIdx.x, lane = tid & 63, w = tid >> 6;   // w: 0..7
    const int col0 = blockIdx.x*2;
    const int k0 = w*128;
    float a0 = 0.f, a1 = 0.f;
    #pragma unroll 4
    for (int k = k0; k < k0+128; ++k){
        float a = ht[(size_t)k*64 + lane];
        __half2 wv = *reinterpret_cast<const __half2*>(Whh + (size_t)k*HD + col0);
        float2 f = __half22float2(wv);
        a0 += a*f.x; a1 += a*f.y;
    }
    part[w][0][lane] = a0;
    part[w][1][lane] = a1;
    __syncthreads();
    if (tid < 128){
        int c = tid >> 6, b = tid & 63;
        int col = col0 + c;
        float v = bh[col];
        #pragma unroll
        for (int w2 = 0; w2 < 8; ++w2) v += part[w2][c][b];
        if (col < 128)       khat[b*256 + col] = tanhf(v);
        else if (col < 134){ int i = col-128; scal[b*16 + i]     = (i==0)?softplusf(v):(i==1)?sigmoidf(v):(i==5)?1.f+softplusf(v):v; }
        else if (col < 262)  khat[b*256 + 128 + (col-134)] = tanhf(v);
        else if (col < 268){ int i = col-262; scal[b*16 + 8 + i] = (i==0)?softplusf(v):(i==1)?sigmoidf(v):(i==5)?1.f+softplusf(v):v; }
        else if (col < 396)  eal[b*256 + (col-268)]        = sigmoidf(v);
        else                 eal[b*256 + 128 + (col-396)]  = tanhf(v);
    }
}

// ---------- K3: Mem row norms + content dots. grid 512 (b*8+nq) x 512 ----------
__global__ __launch_bounds__(512) void k3_dots(
    const float* __restrict__ khat, const __half* __restrict__ Mem,
    float* __restrict__ mnorm, float* __restrict__ dots)
{
    __shared__ float kh[256];
    const int b = blockIdx.x >> 3, nq = blockIdx.x & 7;
    const int tid = threadIdx.x, lane = tid & 63, w = tid >> 6;   // w: 0..7
    if (tid < 256) kh[tid] = khat[b*256 + tid];
    __syncthreads();
    float2 kr  = reinterpret_cast<const float2*>(kh)[lane];
    float2 kw2 = reinterpret_cast<const float2*>(kh + 128)[lane];
    #pragma unroll 2
    for (int i = 0; i < 8; ++i){
        int n = nq*64 + w*8 + i;
        const __half* mrow = Mem + ((size_t)b*N + n)*M;
        __half2 mh = *reinterpret_cast<const __half2*>(mrow + lane*2);
        float2 mv = __half22float2(mh);
        float s2 = mv.x*mv.x + mv.y*mv.y;
        float dr = mv.x*kr.x + mv.y*kr.y;
        float dw = mv.x*kw2.x + mv.y*kw2.y;
        #pragma unroll
        for (int off = 32; off; off >>= 1){
            s2 += __shfl_xor(s2, off);
            dr += __shfl_xor(dr, off);
            dw += __shfl_xor(dw, off);
        }
        if (lane == 0){
            mnorm[b*N + n] = sqrtf(s2);
            dots[(b*2+0)*N + n] = dr;
            dots[(b*2+1)*N + n] = dw;
        }
    }
}

// group-local (512-thread) reductions; both halves call in lockstep
__device__ __forceinline__ float blk_sum8g(float v, volatile float* red8, int lane, int wgi){
    #pragma unroll
    for (int off = 32; off; off >>= 1) v += __shfl_xor(v, off);
    if (lane == 0) red8[wgi] = v;
    __syncthreads();
    float r = red8[0]+red8[1]+red8[2]+red8[3]+red8[4]+red8[5]+red8[6]+red8[7];
    __syncthreads();
    return r;
}
__device__ __forceinline__ float blk_max8g(float v, volatile float* red8, int lane, int wgi){
    #pragma unroll
    for (int off = 32; off; off >>= 1) v = fmaxf(v, __shfl_xor(v, off));
    if (lane == 0) red8[wgi] = v;
    __syncthreads();
    float r = fmaxf(fmaxf(fmaxf(red8[0],red8[1]),fmaxf(red8[2],red8[3])),
                    fmaxf(fmaxf(red8[4],red8[5]),fmaxf(red8[6],red8[7])));
    __syncthreads();
    return r;
}

// ---------- K4: addressing (8x redundant) + Mem update + reads. grid 512 (b*8+nq) x 1024 ----------
__global__ __launch_bounds__(1024) void k4_addr(
    const float* __restrict__ khat, const float* __restrict__ scal, const float* __restrict__ ealg,
    const float* __restrict__ mnorm, const float* __restrict__ dots,
    float* __restrict__ wst, __half* __restrict__ Mem, float* __restrict__ rp, int t)
{
    __shared__ float kh[256];
    __shared__ float sc[16];
    __shared__ float eal[256];
    __shared__ float wfin[1024];
    __shared__ float wgbuf[1024];
    __shared__ float red8[2][8];
    __shared__ float racc_s[1024];
    const int b = blockIdx.x >> 3, nq = blockIdx.x & 7;
    const int tid = threadIdx.x, lane = tid & 63;

    if (tid < 256)      kh[tid]      = khat[b*256 + tid];
    else if (tid < 272) sc[tid-256]  = scal[b*16 + (tid-256)];
    else if (tid < 528) eal[tid-272] = ealg[b*256 + (tid-272)];
    __syncthreads();

    // addressing, both heads in parallel 512-thread halves (8x redundant across siblings)
    {
        const int g = tid >> 9;          // head
        const int n = tid & 511;
        const int wgi = (tid >> 6) & 7;
        float* wgl = wgbuf + g*512;
        volatile float* r8 = red8[g];

        float kv = (n < 128) ? kh[g*128 + n] : 0.f;
        float knm = sqrtf(blk_sum8g(kv*kv, r8, lane, wgi));
        float beta = sc[g*8+0], gg = sc[g*8+1], gamma = sc[g*8+5];
        float s0r = sc[g*8+2], s1r = sc[g*8+3], s2r = sc[g*8+4];
        float smx = fmaxf(s0r, fmaxf(s1r, s2r));
        float e0 = expf(s0r-smx), e1 = expf(s1r-smx), e2 = expf(s2r-smx);
        float esum = e0+e1+e2;
        float s0 = e0/esum, s1 = e1/esum, s2 = e2/esum;

        float sim = dots[(b*2+g)*N + n] / (mnorm[b*N + n]*knm + EPS);
        float aa = beta * sim;
        float amax = blk_max8g(aa, r8, lane, wgi);
        float ev = expf(aa - amax);
        float wc = ev / blk_sum8g(ev, r8, lane, wgi);

        const float* wpr = wst + ((size_t)((t&1)*2 + g))*(B*N);
        float*       wnx = wst + ((size_t)(((t+1)&1)*2 + g))*(B*N);
        float wprev = wpr[b*N + n];
        float wgv = gg*wc + (1.f - gg)*wprev;
        wgl[n] = wgv; __syncthreads();
        float wsv = s0*wgl[(n+1)&511] + s1*wgv + s2*wgl[(n-1)&511];
        float wp2 = powf(wsv + EPS, gamma);
        float wsum = blk_sum8g(wp2, r8, lane, wgi);
        float wv = wp2 / wsum;
        wfin[g*512 + n] = wv;
        if (nq == 0) wnx[b*N + n] = wv;
        __syncthreads();
    }

    // read (old Mem) + erase/add on own (b,nq) slice of 64 rows
    {
        const int m = tid & 127, ns = tid >> 7;   // 8 row-groups
        const float e  = eal[m];
        const float ad = eal[128 + m];
        float racc = 0.f;
        #pragma unroll 4
        for (int i2 = 0; i2 < 8; ++i2){
            int nn = nq*64 + i2*8 + ns;
            size_t idx = ((size_t)b*N + nn)*M + m;
            float v = __half2float(Mem[idx]);
            float wr = wfin[nn], ww = wfin[512 + nn];
            racc += wr*v;
            Mem[idx] = __float2half_rn(v*(1.f - ww*e) + ww*ad);
        }
        racc_s[tid] = racc;
        __syncthreads();
        if (tid < 128){
            float s = 0.f;
            #pragma unroll
            for (int g2 = 0; g2 < 8; ++g2) s += racc_s[g2*128 + tid];
            rp[(size_t)nq*8192 + tid*64 + b] = s;
        }
    }
}

// ---------- k_fin: last step's reads -> hist. grid 32 x 256 ----------
__global__ __launch_bounds__(256) void k_fin(const float* __restrict__ rp, float* __restrict__ hist){
    int e = blockIdx.x*256 + threadIdx.x;
    float s = 0.f;
    #pragma unroll
    for (int p = 0; p < 8; ++p) s += rp[p*8192 + e];
    hist[((size_t)31*K5K + 1024 + (e>>6))*64 + (e&63)] = s;
}

// ---------- K5: out = sigmoid([h, reads]·Wo + bo), all 32 write steps. grid 256 x 512 ----------
__global__ __launch_bounds__(512) void k5_out(
    const float* __restrict__ hist, const float* __restrict__ Wo, const float* __restrict__ bo,
    float* __restrict__ out)
{
    __shared__ float smem[16384];
    const int tid = threadIdx.x, lane = tid & 63, w = tid >> 6;
    const int l = blockIdx.x >> 3, jg = blockIdx.x & 7;
    const int j0 = jg*32;
    float acc[32];
    #pragma unroll
    for (int i = 0; i < 32; ++i) acc[i] = 0.f;
    const int k0 = w*144;
    #pragma unroll 2
    for (int kk = 0; kk < 144; ++kk){
        int k = k0 + kk;
        float a = hist[((size_t)l*K5K + k)*64 + lane];
        const float* wrow = Wo + (size_t)k*D + j0;
        #pragma unroll
        for (int qq = 0; qq < 8; ++qq){
            float4 wv = *reinterpret_cast<const float4*>(wrow + qq*4);
            acc[qq*4+0] += a*wv.x; acc[qq*4+1] += a*wv.y;
            acc[qq*4+2] += a*wv.z; acc[qq*4+3] += a*wv.w;
        }
    }
    __syncthreads();
    #pragma unroll
    for (int c = 0; c < 32; ++c) smem[(w*32 + c)*64 + lane] = acc[c];
    __syncthreads();
    {
        const int b2 = tid >> 3, jq = tid & 7;
        float4 ov;
        float* po = (float*)&ov;
        #pragma unroll
        for (int i = 0; i < 4; ++i){
            int c = jq*4 + i;
            float s = bo[j0 + c];
            #pragma unroll
            for (int ks = 0; ks < 8; ++ks) s += smem[(ks*32 + c)*64 + b2];
            po[i] = sigmoidf(s);
        }
        *reinterpret_cast<float4*>(out + ((size_t)b2*L_WRITE + l)*D + j0 + jq*4) = ov;
    }
}

extern "C" void kernel_launch(void* const* d_in, const int* in_sizes, int n_in,
                              void* d_out, int out_size, void* d_ws, size_t ws_size,
                              hipStream_t stream)
{
    const float* x   = (const float*)d_in[0];
    const float* Wl  = (const float*)d_in[1];
    const float* Ul  = (const float*)d_in[2];
    const float* bl  = (const float*)d_in[3];
    const float* Wh  = (const float*)d_in[4];
    const float* bh  = (const float*)d_in[5];
    const float* Wo  = (const float*)d_in[6];
    const float* bo  = (const float*)d_in[7];
    float* out = (float*)d_out;

    float* ws = (float*)d_ws;
    float* xT    = ws; ws += (size_t)T_READ*D*64;       // 8.4 MB
    __half* Wreh = (__half*)ws; ws += (size_t)1408*4096/2;   // 11.5 MB
    __half* Whh  = (__half*)ws; ws += (size_t)1024*HD/2 + 64;
    float* ht    = ws; ws += (size_t)R*64;
    float* c_t   = ws; ws += (size_t)R*64;
    float* khat  = ws; ws += (size_t)B*256;
    float* scal  = ws; ws += (size_t)B*16;
    float* eal   = ws; ws += (size_t)B*256;
    float* mnorm = ws; ws += (size_t)B*N;
    float* dots  = ws; ws += (size_t)B*2*N;
    float* wst   = ws; ws += (size_t)4*B*N;             // parity x head
    __half* Mem  = (__half*)ws; ws += BNM/2;            // 8.4 MB fp16
    float* rp    = ws; ws += (size_t)8*128*64;
    float* hist  = ws; ws += (size_t)L_WRITE*K5K*64;    // 9.4 MB

    hipLaunchKernelGGL(kx_transpose, dim3(T_READ*4), dim3(256), 0, stream, x, xT);
    hipLaunchKernelGGL(kpack_w,      dim3(1408),     dim3(256), 0, stream, Wl, Ul, Wreh);
    hipLaunchKernelGGL(kpack_wh,     dim3(1024),     dim3(256), 0, stream, Wh, Whh);
    hipLaunchKernelGGL(k_init,       dim3(2048),     dim3(256), 0, stream, ht, c_t, rp, wst, Mem);

    for (int t = 0; t < TT; ++t){
        hipLaunchKernelGGL(k1_z,    dim3(512), dim3(1024), 0, stream, xT, Wreh, bl, ht, c_t, rp, hist, t);
        hipLaunchKernelGGL(k2f,     dim3(262), dim3(512),  0, stream, ht, Whh, bh, khat, scal, eal);
        hipLaunchKernelGGL(k3_dots, dim3(512), dim3(512),  0, stream, khat, Mem, mnorm, dots);
        hipLaunchKernelGGL(k4_addr, dim3(512), dim3(1024), 0, stream, khat, scal, eal, mnorm, dots, wst, Mem, rp, t);
    }
    hipLaunchKernelGGL(k_fin,  dim3(32),  dim3(256), 0, stream, rp, hist);
    hipLaunchKernelGGL(k5_out, dim3(256), dim3(512), 0, stream, hist, Wo, bo, out);
}

// Round 20
// 10623.105 us; speedup vs baseline: 1.2385x; 1.2385x over previous
//
#include <hip/hip_runtime.h>
#include <hip/hip_fp16.h>
#include <math.h>

#define B 64
#define T_READ 128
#define L_WRITE 32
#define TT 160
#define D 256
#define R 1024
#define N 512
#define M 128
#define HD 524
#define K5K 1152
#define EPS 1e-8f
#define BNM ((size_t)B*N*M)

__device__ __forceinline__ float sigmoidf(float x){ return 1.0f/(1.0f+expf(-x)); }
__device__ __forceinline__ float softplusf(float x){ return (x > 20.f) ? x : log1pf(expf(x)); }

// ---------- one-time: transpose x -> xT[t][k][b] ----------
__global__ __launch_bounds__(256) void kx_transpose(const float* __restrict__ x, float* __restrict__ xT){
    __shared__ float tile[64][65];
    const int t = blockIdx.x >> 2, k0 = (blockIdx.x & 3)*64;
    #pragma unroll
    for (int rep = 0; rep < 16; ++rep){
        int idx = rep*256 + threadIdx.x;
        int bl = idx >> 6, kl = idx & 63;
        tile[bl][kl] = x[((size_t)bl*T_READ + t)*D + k0 + kl];
    }
    __syncthreads();
    #pragma unroll
    for (int rep = 0; rep < 16; ++rep){
        int idx = rep*256 + threadIdx.x;
        int kl = idx >> 6, bl = idx & 63;
        xT[((size_t)t*D + k0 + kl)*64 + bl] = tile[bl][kl];
    }
}

// ---------- one-time: pack Wl/Ul into per-block-contiguous fp16 Wreh[bk][k][16] ----------
__global__ __launch_bounds__(256) void kpack_w(const float* __restrict__ Wl, const float* __restrict__ Ul,
                                               __half* __restrict__ Wreh){
    const int k = blockIdx.x;                 // 0..1407
    const float* src = (k < 384) ? (Wl + (size_t)k*4096) : (Ul + (size_t)(k-384)*4096);
    #pragma unroll
    for (int it = 0; it < 16; ++it){
        int j = it*256 + threadIdx.x;         // 0..4095
        int bk = j >> 4, r = j & 15, q = r >> 2, i = r & 3;
        Wreh[((size_t)bk*1408 + k)*16 + r] = __float2half_rn(src[q*1024 + bk*4 + i]);
    }
}

// ---------- one-time: Wh -> fp16 copy ----------
__global__ __launch_bounds__(256) void kpack_wh(const float* __restrict__ Wh, __half* __restrict__ Whh){
    const int k = blockIdx.x;                 // 0..1023
    for (int j = threadIdx.x; j < HD; j += 256)
        Whh[(size_t)k*HD + j] = __float2half_rn(Wh[(size_t)k*HD + j]);
}

// ---------- one-time: init state ----------
__global__ void k_init(float* ht, float* c_t, float* reads_fin, float* wst, __half* Mem){
    size_t idx = (size_t)blockIdx.x*blockDim.x + threadIdx.x;
    size_t stride = (size_t)gridDim.x*blockDim.x;
    const __half mi = __float2half(1e-6f);
    for (size_t i = idx; i < BNM; i += stride) Mem[i] = mi;
    for (size_t i = idx; i < R*64; i += stride){ ht[i]=0.f; c_t[i]=0.f; }
    for (size_t i = idx; i < 2*128*64; i += stride) reads_fin[i] = 0.f;
    for (size_t i = idx; i < 4*B*N; i += stride) wst[i] = 1.f/512.f;
}

// ---------- K1: z-GEMM (reads direct from finalized buffer); LSTM gates. grid 256 x 1024 ----------
__global__ __launch_bounds__(1024) void k1_z(
    const float* __restrict__ xT, const __half* __restrict__ Wreh, const float* __restrict__ bl,
    float* __restrict__ ht, float* __restrict__ c_t, const float* __restrict__ reads_fin,
    float* __restrict__ hist, int t)
{
    __shared__ float comb[16384];
    const int bk = blockIdx.x;
    const int tid = threadIdx.x, lane = tid & 63, w = tid >> 6;   // w: 0..15
    const float* rf = reads_fin + (size_t)(t & 1)*8192;

    if (t > T_READ && bk < 8){
        int e = bk*1024 + tid;
        hist[((size_t)(t-1-T_READ)*K5K + 1024 + (e>>6))*64 + (e&63)] = rf[e];
    }

    const int r0 = bk*4;
    const int rd = (t < T_READ);
    const int kn = rd ? 88 : 72;
    const int k0 = rd ? w*88 : 256 + w*72;
    const __half* wbase = Wreh + ((size_t)bk*1408 + k0)*16;
    float acc[16];
    #pragma unroll
    for (int i = 0; i < 16; ++i) acc[i] = 0.f;
    #pragma unroll 4
    for (int kk = 0; kk < kn; ++kk){
        int k = k0 + kk;
        float a;
        if (k < 256)      a = xT[((size_t)t*256 + k)*64 + lane];
        else if (k < 384) a = rf[(k-256)*64 + lane];
        else              a = ht[(size_t)(k-384)*64 + lane];
        float4 raw0 = *reinterpret_cast<const float4*>(wbase + (size_t)kk*16);
        float4 raw1 = *reinterpret_cast<const float4*>(wbase + (size_t)kk*16 + 8);
        const __half2* h0 = reinterpret_cast<const __half2*>(&raw0);
        const __half2* h1 = reinterpret_cast<const __half2*>(&raw1);
        float2 f;
        f = __half22float2(h0[0]); acc[0] += a*f.x; acc[1] += a*f.y;
        f = __half22float2(h0[1]); acc[2] += a*f.x; acc[3] += a*f.y;
        f = __half22float2(h0[2]); acc[4] += a*f.x; acc[5] += a*f.y;
        f = __half22float2(h0[3]); acc[6] += a*f.x; acc[7] += a*f.y;
        f = __half22float2(h1[0]); acc[8] += a*f.x; acc[9] += a*f.y;
        f = __half22float2(h1[1]); acc[10]+= a*f.x; acc[11]+= a*f.y;
        f = __half22float2(h1[2]); acc[12]+= a*f.x; acc[13]+= a*f.y;
        f = __half22float2(h1[3]); acc[14]+= a*f.x; acc[15]+= a*f.y;
    }
    #pragma unroll
    for (int j = 0; j < 16; ++j) comb[(w*16 + j)*64 + lane] = acc[j];
    __syncthreads();
    if (tid < 256){
        int i = tid >> 6, b2 = tid & 63;
        float g4[4];
        #pragma unroll
        for (int q = 0; q < 4; ++q){
            float s = bl[q*1024 + r0 + i];
            #pragma unroll
            for (int ks = 0; ks < 16; ++ks) s += comb[(ks*16 + q*4 + i)*64 + b2];
            g4[q] = s;
        }
        int ri = (r0 + i)*64 + b2;
        float cn = sigmoidf(g4[1])*c_t[ri] + sigmoidf(g4[0])*tanhf(g4[2]);
        float hn = sigmoidf(g4[3])*tanhf(cn);
        c_t[ri] = cn;
        ht[ri] = hn;
        if (t >= T_READ) hist[((size_t)(t-T_READ)*K5K + r0 + i)*64 + b2] = hn;
    }
}

// ---------- K2f: head GEMM + finalize, fused. grid 262 x 1024 (16-way ksplit of 64) ----------
__global__ __launch_bounds__(1024) void k2f(
    const float* __restrict__ ht, const __half* __restrict__ Whh, const float* __restrict__ bh,
    float* __restrict__ khat, float* __restrict__ scal, float* __restrict__ eal)
{
    __shared__ float part[16][2][64];
    const int tid = threadIdx.x, lane = tid & 63, w = tid >> 6;   // w: 0..15
    const int col0 = blockIdx.x*2;
    const int k0 = w*64;
    float a0 = 0.f, a1 = 0.f;
    #pragma unroll 4
    for (int k = k0; k < k0+64; ++k){
        float a = ht[(size_t)k*64 + lane];
        __half2 wv = *reinterpret_cast<const __half2*>(Whh + (size_t)k*HD + col0);
        float2 f = __half22float2(wv);
        a0 += a*f.x; a1 += a*f.y;
    }
    part[w][0][lane] = a0;
    part[w][1][lane] = a1;
    __syncthreads();
    if (tid < 128){
        int c = tid >> 6, b = tid & 63;
        int col = col0 + c;
        float v = bh[col];
        #pragma unroll
        for (int w2 = 0; w2 < 16; ++w2) v += part[w2][c][b];
        if (col < 128)       khat[b*256 + col] = tanhf(v);
        else if (col < 134){ int i = col-128; scal[b*16 + i]     = (i==0)?softplusf(v):(i==1)?sigmoidf(v):(i==5)?1.f+softplusf(v):v; }
        else if (col < 262)  khat[b*256 + 128 + (col-134)] = tanhf(v);
        else if (col < 268){ int i = col-262; scal[b*16 + 8 + i] = (i==0)?softplusf(v):(i==1)?sigmoidf(v):(i==5)?1.f+softplusf(v):v; }
        else if (col < 396)  eal[b*256 + (col-268)]        = sigmoidf(v);
        else                 eal[b*256 + 128 + (col-396)]  = tanhf(v);
    }
}

// ---------- K3: Mem row norms + content dots; zero consumed reads buffer. grid 512 (b*8+nq) x 512 ----------
__global__ __launch_bounds__(512) void k3_dots(
    const float* __restrict__ khat, const __half* __restrict__ Mem,
    float* __restrict__ mnorm, float* __restrict__ dots, float* __restrict__ reads_fin, int t)
{
    __shared__ float kh[256];
    const int b = blockIdx.x >> 3, nq = blockIdx.x & 7;
    const int tid = threadIdx.x, lane = tid & 63, w = tid >> 6;   // w: 0..7
    if (blockIdx.x < 8){
        int e = blockIdx.x*1024 + tid;
        reads_fin[(size_t)(t & 1)*8192 + e] = 0.f;
        reads_fin[(size_t)(t & 1)*8192 + e + 512] = 0.f;
    }
    if (tid < 256) kh[tid] = khat[b*256 + tid];
    __syncthreads();
    float2 kr  = reinterpret_cast<const float2*>(kh)[lane];
    float2 kw2 = reinterpret_cast<const float2*>(kh + 128)[lane];
    #pragma unroll 2
    for (int i = 0; i < 8; ++i){
        int n = nq*64 + w*8 + i;
        const __half* mrow = Mem + ((size_t)b*N + n)*M;
        __half2 mh = *reinterpret_cast<const __half2*>(mrow + lane*2);
        float2 mv = __half22float2(mh);
        float s2 = mv.x*mv.x + mv.y*mv.y;
        float dr = mv.x*kr.x + mv.y*kr.y;
        float dw = mv.x*kw2.x + mv.y*kw2.y;
        #pragma unroll
        for (int off = 32; off; off >>= 1){
            s2 += __shfl_xor(s2, off);
            dr += __shfl_xor(dr, off);
            dw += __shfl_xor(dw, off);
        }
        if (lane == 0){
            mnorm[b*N + n] = sqrtf(s2);
            dots[(b*2+0)*N + n] = dr;
            dots[(b*2+1)*N + n] = dw;
        }
    }
}

// group-local (512-thread) reductions; both halves call in lockstep
__device__ __forceinline__ float blk_sum8g(float v, volatile float* red8, int lane, int wgi){
    #pragma unroll
    for (int off = 32; off; off >>= 1) v += __shfl_xor(v, off);
    if (lane == 0) red8[wgi] = v;
    __syncthreads();
    float r = red8[0]+red8[1]+red8[2]+red8[3]+red8[4]+red8[5]+red8[6]+red8[7];
    __syncthreads();
    return r;
}
__device__ __forceinline__ float blk_max8g(float v, volatile float* red8, int lane, int wgi){
    #pragma unroll
    for (int off = 32; off; off >>= 1) v = fmaxf(v, __shfl_xor(v, off));
    if (lane == 0) red8[wgi] = v;
    __syncthreads();
    float r = fmaxf(fmaxf(fmaxf(red8[0],red8[1]),fmaxf(red8[2],red8[3])),
                    fmaxf(fmaxf(red8[4],red8[5]),fmaxf(red8[6],red8[7])));
    __syncthreads();
    return r;
}

// ---------- K4: addressing (8x redundant) + Mem update + atomic reads finalize. grid 512 x 1024 ----------
__global__ __launch_bounds__(1024) void k4_addr(
    const float* __restrict__ khat, const float* __restrict__ scal, const float* __restrict__ ealg,
    const float* __restrict__ mnorm, const float* __restrict__ dots,
    float* __restrict__ wst, __half* __restrict__ Mem, float* __restrict__ reads_fin, int t)
{
    __shared__ float kh[256];
    __shared__ float sc[16];
    __shared__ float eal[256];
    __shared__ float wfin[1024];
    __shared__ float wgbuf[1024];
    __shared__ float red8[2][8];
    __shared__ float racc_s[1024];
    const int b = blockIdx.x >> 3, nq = blockIdx.x & 7;
    const int tid = threadIdx.x, lane = tid & 63;

    if (tid < 256)      kh[tid]      = khat[b*256 + tid];
    else if (tid < 272) sc[tid-256]  = scal[b*16 + (tid-256)];
    else if (tid < 528) eal[tid-272] = ealg[b*256 + (tid-272)];
    __syncthreads();

    // addressing, both heads in parallel 512-thread halves (8x redundant across siblings)
    {
        const int g = tid >> 9;          // head
        const int n = tid & 511;
        const int wgi = (tid >> 6) & 7;
        float* wgl = wgbuf + g*512;
        volatile float* r8 = red8[g];

        float kv = (n < 128) ? kh[g*128 + n] : 0.f;
        float knm = sqrtf(blk_sum8g(kv*kv, r8, lane, wgi));
        float beta = sc[g*8+0], gg = sc[g*8+1], gamma = sc[g*8+5];
        float s0r = sc[g*8+2], s1r = sc[g*8+3], s2r = sc[g*8+4];
        float smx = fmaxf(s0r, fmaxf(s1r, s2r));
        float e0 = expf(s0r-smx), e1 = expf(s1r-smx), e2 = expf(s2r-smx);
        float esum = e0+e1+e2;
        float s0 = e0/esum, s1 = e1/esum, s2 = e2/esum;

        float sim = dots[(b*2+g)*N + n] / (mnorm[b*N + n]*knm + EPS);
        float aa = beta * sim;
        float amax = blk_max8g(aa, r8, lane, wgi);
        float ev = expf(aa - amax);
        float wc = ev / blk_sum8g(ev, r8, lane, wgi);

        const float* wpr = wst + ((size_t)((t&1)*2 + g))*(B*N);
        float*       wnx = wst + ((size_t)(((t+1)&1)*2 + g))*(B*N);
        float wprev = wpr[b*N + n];
        float wgv = gg*wc + (1.f - gg)*wprev;
        wgl[n] = wgv; __syncthreads();
        float wsv = s0*wgl[(n+1)&511] + s1*wgv + s2*wgl[(n-1)&511];
        float wp2 = powf(wsv + EPS, gamma);
        float wsum = blk_sum8g(wp2, r8, lane, wgi);
        float wv = wp2 / wsum;
        wfin[g*512 + n] = wv;
        if (nq == 0) wnx[b*N + n] = wv;
        __syncthreads();
    }

    // read (old Mem) + erase/add on own (b,nq) slice of 64 rows; atomic finalize
    {
        const int m = tid & 127, ns = tid >> 7;   // 8 row-groups
        const float e  = eal[m];
        const float ad = eal[128 + m];
        float racc = 0.f;
        #pragma unroll 4
        for (int i2 = 0; i2 < 8; ++i2){
            int nn = nq*64 + i2*8 + ns;
            size_t idx = ((size_t)b*N + nn)*M + m;
            float v = __half2float(Mem[idx]);
            float wr = wfin[nn], ww = wfin[512 + nn];
            racc += wr*v;
            Mem[idx] = __float2half_rn(v*(1.f - ww*e) + ww*ad);
        }
        racc_s[tid] = racc;
        __syncthreads();
        if (tid < 128){
            float s = 0.f;
            #pragma unroll
            for (int g2 = 0; g2 < 8; ++g2) s += racc_s[g2*128 + tid];
            atomicAdd(&reads_fin[(size_t)((t+1) & 1)*8192 + tid*64 + b], s);
        }
    }
}

// ---------- k_fin: last step's reads -> hist. grid 32 x 256 ----------
__global__ __launch_bounds__(256) void k_fin(const float* __restrict__ reads_fin, float* __restrict__ hist){
    int e = blockIdx.x*256 + threadIdx.x;
    float s = reads_fin[(size_t)(TT & 1)*8192 + e];
    hist[((size_t)31*K5K + 1024 + (e>>6))*64 + (e&63)] = s;
}

// ---------- K5: out = sigmoid([h, reads]·Wo + bo), all 32 write steps. grid 256 x 512 ----------
__global__ __launch_bounds__(512) void k5_out(
    const float* __restrict__ hist, const float* __restrict__ Wo, const float* __restrict__ bo,
    float* __restrict__ out)
{
    __shared__ float smem[16384];
    const int tid = threadIdx.x, lane = tid & 63, w = tid >> 6;
    const int l = blockIdx.x >> 3, jg = blockIdx.x & 7;
    const int j0 = jg*32;
    float acc[32];
    #pragma unroll
    for (int i = 0; i < 32; ++i) acc[i] = 0.f;
    const int k0 = w*144;
    #pragma unroll 2
    for (int kk = 0; kk < 144; ++kk){
        int k = k0 + kk;
        float a = hist[((size_t)l*K5K + k)*64 + lane];
        const float* wrow = Wo + (size_t)k*D + j0;
        #pragma unroll
        for (int qq = 0; qq < 8; ++qq){
            float4 wv = *reinterpret_cast<const float4*>(wrow + qq*4);
            acc[qq*4+0] += a*wv.x; acc[qq*4+1] += a*wv.y;
            acc[qq*4+2] += a*wv.z; acc[qq*4+3] += a*wv.w;
        }
    }
    __syncthreads();
    #pragma unroll
    for (int c = 0; c < 32; ++c) smem[(w*32 + c)*64 + lane] = acc[c];
    __syncthreads();
    {
        const int b2 = tid >> 3, jq = tid & 7;
        float4 ov;
        float* po = (float*)&ov;
        #pragma unroll
        for (int i = 0; i < 4; ++i){
            int c = jq*4 + i;
            float s = bo[j0 + c];
            #pragma unroll
            for (int ks = 0; ks < 8; ++ks) s += smem[(ks*32 + c)*64 + b2];
            po[i] = sigmoidf(s);
        }
        *reinterpret_cast<float4*>(out + ((size_t)b2*L_WRITE + l)*D + j0 + jq*4) = ov;
    }
}

extern "C" void kernel_launch(void* const* d_in, const int* in_sizes, int n_in,
                              void* d_out, int out_size, void* d_ws, size_t ws_size,
                              hipStream_t stream)
{
    const float* x   = (const float*)d_in[0];
    const float* Wl  = (const float*)d_in[1];
    const float* Ul  = (const float*)d_in[2];
    const float* bl  = (const float*)d_in[3];
    const float* Wh  = (const float*)d_in[4];
    const float* bh  = (const float*)d_in[5];
    const float* Wo  = (const float*)d_in[6];
    const float* bo  = (const float*)d_in[7];
    float* out = (float*)d_out;

    float* ws = (float*)d_ws;
    float* xT    = ws; ws += (size_t)T_READ*D*64;       // 8.4 MB
    __half* Wreh = (__half*)ws; ws += (size_t)1408*4096/2;   // 11.5 MB
    __half* Whh  = (__half*)ws; ws += (size_t)1024*HD/2 + 64;
    float* ht    = ws; ws += (size_t)R*64;
    float* c_t   = ws; ws += (size_t)R*64;
    float* khat  = ws; ws += (size_t)B*256;
    float* scal  = ws; ws += (size_t)B*16;
    float* eal   = ws; ws += (size_t)B*256;
    float* mnorm = ws; ws += (size_t)B*N;
    float* dots  = ws; ws += (size_t)B*2*N;
    float* wst   = ws; ws += (size_t)4*B*N;             // parity x head
    __half* Mem  = (__half*)ws; ws += BNM/2;            // 8.4 MB fp16
    float* reads_fin = ws; ws += (size_t)2*128*64;      // parity double-buffered
    float* hist  = ws; ws += (size_t)L_WRITE*K5K*64;    // 9.4 MB

    hipLaunchKernelGGL(kx_transpose, dim3(T_READ*4), dim3(256), 0, stream, x, xT);
    hipLaunchKernelGGL(kpack_w,      dim3(1408),     dim3(256), 0, stream, Wl, Ul, Wreh);
    hipLaunchKernelGGL(kpack_wh,     dim3(1024),     dim3(256), 0, stream, Wh, Whh);
    hipLaunchKernelGGL(k_init,       dim3(2048),     dim3(256), 0, stream, ht, c_t, reads_fin, wst, Mem);

    for (int t = 0; t < TT; ++t){
        hipLaunchKernelGGL(k1_z,    dim3(256), dim3(1024), 0, stream, xT, Wreh, bl, ht, c_t, reads_fin, hist, t);
        hipLaunchKernelGGL(k2f,     dim3(262), dim3(1024), 0, stream, ht, Whh, bh, khat, scal, eal);
        hipLaunchKernelGGL(k3_dots, dim3(512), dim3(512),  0, stream, khat, Mem, mnorm, dots, reads_fin, t);
        hipLaunchKernelGGL(k4_addr, dim3(512), dim3(1024), 0, stream, khat, scal, eal, mnorm, dots, wst, Mem, reads_fin, t);
    }
    hipLaunchKernelGGL(k_fin,  dim3(32),  dim3(256), 0, stream, reads_fin, hist);
    hipLaunchKernelGGL(k5_out, dim3(256), dim3(512), 0, stream, hist, Wo, bo, out);
}